// Round 2
// baseline (99.957 us; speedup 1.0000x reference)
//
#include <hip/hip_runtime.h>
#include <math.h>

#define NB 256     // N nodes
#define CH 64      // C input features
#define OUTF 64    // O output features
#define GK 8       // GRID_SIZE + SPLINE_ORDER
#define UIN 128    // update-KAN input dim (C + O)
#define KM (CH * 9)    // 576 feature rows for msg KAN (8 spline + 1 silu per ch)
#define KM4 (KM / 4)   // 144
#define KU (UIN * 9)   // 1152 feature rows for update KAN
#define KU4 (KU / 4)   // 288

// workspace layout in floats
#define WS_MSG 0                     // 512*64            = 32768
#define WS_W2M 32768                 // 144*64*4          = 36864
#define WS_W2U 69632                 // 288*64*4          = 73728
#define WS_CPAD 143360               // 64*16*4           = 4096
// total 147456 floats = 576 KB

__device__ __forceinline__ float silu(float v) {
    return v * __builtin_amdgcn_rcpf(1.0f + __expf(-v));
}

// Uniform cubic B-spline, knots t(m)=0.4m-2.2. Interval d=floor((r+2.2)*2.5),
// u=frac. 4 nonzero bases m=d-3..d with segment polys
// {(1-u)^3, 3u^3-6u^2+4, -3u^3+3u^2+3u+1, u^3}/6. Out of grid -> d=11 (zeros).
__device__ __forceinline__ void spline4(float r, int& d, float4& v) {
    float p = fmaf(r, 2.5f, 5.5f);   // (r+2.2)*2.5
    float fd = floorf(p);
    d = (int)fd;
    float u = p - fd;
    if ((unsigned)d > 10u) d = 11;
    float um = 1.0f - u;
    float u2 = u * u, u3 = u2 * u;
    const float k6 = 1.0f / 6.0f;
    v.x = um * um * um * k6;
    v.y = (3.0f * u3 - 6.0f * u2 + 4.0f) * k6;
    v.z = (-3.0f * u3 + 3.0f * u2 + 3.0f * u + 1.0f) * k6;
    v.w = u3 * k6;
}

// Prep: folded/transposed W2m + W2u tables, plus the block-invariant cpad
// cubic-coefficient table for the energy KAN (was rebuilt per gat block).
__global__ __launch_bounds__(256) void prep_kernel(
    const float* __restrict__ mwb, const float* __restrict__ mws,
    const float* __restrict__ mwsc,
    const float* __restrict__ uwb, const float* __restrict__ uws,
    const float* __restrict__ uwsc,
    const float* __restrict__ fws, const float* __restrict__ fwsc,
    float* __restrict__ ws) {
    int t = blockIdx.x * 256 + threadIdx.x;
    if (t < KM4 * OUTF) {                        // W2m[k4][o] float4 over k
        int k4 = t >> 6, o = t & 63;
        float4 v;
#pragma unroll
        for (int kk = 0; kk < 4; ++kk) {
            int k = k4 * 4 + kk, c = k / 9, g = k - c * 9;
            ((float*)&v)[kk] = (g < 8)
                ? mws[(o * CH + c) * GK + g] * mwsc[o * CH + c]
                : mwb[o * CH + c];
        }
        ((float4*)(ws + WS_W2M))[t] = v;
        return;
    }
    int t2 = t - KM4 * OUTF;
    if (t2 < KU4 * OUTF) {                       // W2u[k4][o] float4 over k
        int k4 = t2 >> 6, o = t2 & 63;
        float4 v;
#pragma unroll
        for (int kk = 0; kk < 4; ++kk) {
            int k = k4 * 4 + kk, c = k / 9, g = k - c * 9;
            ((float*)&v)[kk] = (g < 8)
                ? uws[(o * UIN + c) * GK + g] * uwsc[o * UIN + c]
                : uwb[o * UIN + c];
        }
        ((float4*)(ws + WS_W2U))[t2] = v;
        return;
    }
    int t3 = t2 - KU4 * OUTF;
    if (t3 < CH * 16) {                          // cpad[c][d] cubic coefs
        int c = t3 >> 4, dd = t3 & 15;
        float4 cf = make_float4(0.f, 0.f, 0.f, 0.f);
        if (dd <= 10) {
            float sc = fwsc[c];
            float w0 = 0.f, w1 = 0.f, w2 = 0.f, w3 = 0.f;
            int m0 = dd - 3;
            if ((unsigned)(m0 + 0) < 8u) w0 = fws[c * GK + m0 + 0] * sc;
            if ((unsigned)(m0 + 1) < 8u) w1 = fws[c * GK + m0 + 1] * sc;
            if ((unsigned)(m0 + 2) < 8u) w2 = fws[c * GK + m0 + 2] * sc;
            if ((unsigned)(m0 + 3) < 8u) w3 = fws[c * GK + m0 + 3] * sc;
            cf.x = (w0 + 4.0f * w1 + w2) * (1.0f / 6.0f);
            cf.y = (w2 - w0) * 0.5f;
            cf.z = (w0 - 2.0f * w1 + w2) * 0.5f;
            cf.w = (w3 - w0 + 3.0f * (w1 - w2)) * (1.0f / 6.0f);
        }
        ((float4*)(ws + WS_CPAD))[t3] = cf;
    }
}

// msg: 2 rows per block; each W2m float4 load feeds both rows.
__global__ __launch_bounds__(256) void msg_kernel(
    const float* __restrict__ x, const float* __restrict__ w2m,
    float* __restrict__ msg) {
    const int r0 = blockIdx.x * 2, tid = threadIdx.x;
    __shared__ __align__(16) float F0[KM];
    __shared__ __align__(16) float F1[KM];
    __shared__ float pa[4][OUTF];
    __shared__ float pb[4][OUTF];

    if (tid < 2 * CH) {
        int rr = tid >> 6, c = tid & 63;
        float* Fr = rr ? F1 : F0;
        float v = x[(r0 + rr) * CH + c];
#pragma unroll
        for (int g = 0; g < 8; ++g) Fr[c * 9 + g] = 0.0f;
        Fr[c * 9 + 8] = silu(v);
        int d; float4 vv; spline4(v, d, vv);
#pragma unroll
        for (int k = 0; k < 4; ++k) {
            int m = d - 3 + k;
            if ((unsigned)m < 8u) Fr[c * 9 + m] = ((const float*)&vv)[k];
        }
    }
    __syncthreads();

    const int o = tid & 63, w = tid >> 6;
    const float4* W = (const float4*)w2m;
    const float4* Fv0 = (const float4*)F0;
    const float4* Fv1 = (const float4*)F1;
    float a0 = 0.0f, a1 = 0.0f;
#pragma unroll 4
    for (int k4 = w * 36; k4 < w * 36 + 36; ++k4) {
        float4 f0 = Fv0[k4];               // uniform LDS b128 broadcast
        float4 f1 = Fv1[k4];
        float4 wt = W[k4 * 64 + o];        // coalesced, reused for 2 rows
        a0 += f0.x * wt.x + f0.y * wt.y + f0.z * wt.z + f0.w * wt.w;
        a1 += f1.x * wt.x + f1.y * wt.y + f1.z * wt.z + f1.w * wt.w;
    }
    pa[w][o] = a0;
    pb[w][o] = a1;
    __syncthreads();
    if (tid < OUTF)
        msg[r0 * OUTF + tid] = pa[0][tid] + pa[1][tid] + pa[2][tid] + pa[3][tid];
    else if (tid < 2 * OUTF) {
        int o2 = tid - OUTF;
        msg[(r0 + 1) * OUTF + o2] = pb[0][o2] + pb[1][o2] + pb[2][o2] + pb[3][o2];
    }
}

// One block per row-pair (b, i0=2p, i1=2p+1): energy -> softmax -> aggregate
// -> update KAN. Every global table load (cpad, msg, W2u) is reused 2x.
__global__ __launch_bounds__(256) void gat_kernel(
    const float* __restrict__ x,     // (B, N, C)
    const int* __restrict__ adj,
    const float* __restrict__ fwb,
    const float* __restrict__ cpadg, // (CH*16) float4 from prep
    const float* __restrict__ w2u,   // (KU4*64) float4
    const float* __restrict__ msg,   // (B, N, O)
    float* __restrict__ out) {
    const int b = blockIdx.x >> 7;
    const int i0 = (blockIdx.x & 127) * 2;
    const int i1 = i0 + 1;
    const int tid = threadIdx.x;     // == j in energy phase

    __shared__ float4 cpad[CH][16];  // per-interval cubic coefs (zero-padded)
    __shared__ float4 xi0_4[16];     // x_i0 row
    __shared__ float4 xi1_4[16];     // x_i1 row
    __shared__ float4 fb4[16];       // fwb
    __shared__ float alpha0[NB];
    __shared__ float alpha1[NB];
    __shared__ float comb0[UIN];
    __shared__ float comb1[UIN];
    __shared__ __align__(16) float Fu0[KU];
    __shared__ __align__(16) float Fu1[KU];
    __shared__ float4 p4a[16][16];   // aggr partials row0
    __shared__ float4 p4b[16][16];   // aggr partials row1
    __shared__ float p2a[4][OUTF];   // matvec partials row0
    __shared__ float p2b[4][OUTF];   // matvec partials row1
    __shared__ float wredA[4], wredB[4];

    // Register-preload this thread's j-row of x (j = tid); latency hides
    // under the LDS setup below. Reused for BOTH energy rows.
    float4 xj[16];
    {
        const float4* xrow = (const float4*)(x + (b * NB + tid) * CH);
#pragma unroll
        for (int c4 = 0; c4 < 16; ++c4) xj[c4] = xrow[c4];
    }

    if (tid < 16) {
        float4 v = ((const float4*)(x + (b * NB + i0) * CH))[tid];
        xi0_4[tid] = v;
        ((float4*)comb0)[tid] = v;
    } else if (tid < 32) {
        float4 v = ((const float4*)(x + (b * NB + i1) * CH))[tid - 16];
        xi1_4[tid - 16] = v;
        ((float4*)comb1)[tid - 16] = v;
    } else if (tid < 48) {
        fb4[tid - 32] = ((const float4*)fwb)[tid - 32];
    }
    // load precomputed cpad: 1024 float4, coalesced
    {
        const float4* cp = (const float4*)cpadg;
        float4* cds = (float4*)cpad;
#pragma unroll
        for (int k = 0; k < 4; ++k) cds[tid + k * 256] = cp[tid + k * 256];
    }
    __syncthreads();

    // ---- energy(i0/i1, j=tid): x-row in registers + LDS b128 coef gather ----
    float e0 = 0.0f, e1 = 0.0f;
#pragma unroll
    for (int c4 = 0; c4 < 16; ++c4) {
        float4 xiv0 = xi0_4[c4];           // uniform b128 broadcast
        float4 xiv1 = xi1_4[c4];
        float4 fbv = fb4[c4];
        float4 xjv = xj[c4];               // registers
#pragma unroll
        for (int q = 0; q < 4; ++q) {
            float xq = ((const float*)&xjv)[q];
            float fb = ((const float*)&fbv)[q];
            {
                float r = ((const float*)&xiv0)[q] - xq;
                float pp = fmaf(r, 2.5f, 5.5f);
                float fd = floorf(pp);
                int d = (int)fd;
                float u = pp - fd;
                if ((unsigned)d > 10u) d = 11;
                float4 cf = cpad[c4 * 4 + q][d];
                float t = fmaf(u, cf.w, cf.z);
                t = fmaf(u, t, cf.y);
                t = fmaf(u, t, cf.x);
                e0 += fmaf(silu(r), fb, t);
            }
            {
                float r = ((const float*)&xiv1)[q] - xq;
                float pp = fmaf(r, 2.5f, 5.5f);
                float fd = floorf(pp);
                int d = (int)fd;
                float u = pp - fd;
                if ((unsigned)d > 10u) d = 11;
                float4 cf = cpad[c4 * 4 + q][d];
                float t = fmaf(u, cf.w, cf.z);
                t = fmaf(u, t, cf.y);
                t = fmaf(u, t, cf.x);
                e1 += fmaf(silu(r), fb, t);
            }
        }
    }
    if (adj[(b * NB + i0) * NB + tid] == 0) e0 = -1e9f;
    if (adj[(b * NB + i1) * NB + tid] == 0) e1 = -1e9f;

    // ---- softmax over j, both rows ----
    float mx0 = e0, mx1 = e1;
#pragma unroll
    for (int off = 32; off > 0; off >>= 1) {
        mx0 = fmaxf(mx0, __shfl_xor(mx0, off, 64));
        mx1 = fmaxf(mx1, __shfl_xor(mx1, off, 64));
    }
    if ((tid & 63) == 0) { wredA[tid >> 6] = mx0; wredB[tid >> 6] = mx1; }
    __syncthreads();
    mx0 = fmaxf(fmaxf(wredA[0], wredA[1]), fmaxf(wredA[2], wredA[3]));
    mx1 = fmaxf(fmaxf(wredB[0], wredB[1]), fmaxf(wredB[2], wredB[3]));
    float p0 = __expf(e0 - mx0), p1 = __expf(e1 - mx1);
    float s0 = p0, s1 = p1;
#pragma unroll
    for (int off = 32; off > 0; off >>= 1) {
        s0 += __shfl_xor(s0, off, 64);
        s1 += __shfl_xor(s1, off, 64);
    }
    __syncthreads();
    if ((tid & 63) == 0) { wredA[tid >> 6] = s0; wredB[tid >> 6] = s1; }
    __syncthreads();
    float den0 = wredA[0] + wredA[1] + wredA[2] + wredA[3];
    float den1 = wredB[0] + wredB[1] + wredB[2] + wredB[3];
    alpha0[tid] = p0 * __builtin_amdgcn_rcpf(den0);
    alpha1[tid] = p1 * __builtin_amdgcn_rcpf(den1);
    __syncthreads();

    // ---- aggr[o] = sum_j alpha[j]*msg[b,j,o]; msg b128 reused for 2 rows ----
    {
        const int o4 = tid & 15, seg = tid >> 4;   // 16 segs x 16 j each
        const float4* msgb4 = (const float4*)(msg + (b * NB + seg * 16) * OUTF);
        float4 a0 = make_float4(0.f, 0.f, 0.f, 0.f);
        float4 a1 = make_float4(0.f, 0.f, 0.f, 0.f);
#pragma unroll
        for (int jj = 0; jj < 16; ++jj) {
            float al0 = alpha0[seg * 16 + jj];
            float al1 = alpha1[seg * 16 + jj];
            float4 mv = msgb4[jj * 16 + o4];       // coalesced b128
            a0.x = fmaf(al0, mv.x, a0.x); a0.y = fmaf(al0, mv.y, a0.y);
            a0.z = fmaf(al0, mv.z, a0.z); a0.w = fmaf(al0, mv.w, a0.w);
            a1.x = fmaf(al1, mv.x, a1.x); a1.y = fmaf(al1, mv.y, a1.y);
            a1.z = fmaf(al1, mv.z, a1.z); a1.w = fmaf(al1, mv.w, a1.w);
        }
        p4a[seg][o4] = a0;
        p4b[seg][o4] = a1;
    }
    __syncthreads();
    if (tid < OUTF) {
        const float* p = (const float*)p4a;
        float s = 0.0f;
#pragma unroll
        for (int sg = 0; sg < 16; ++sg) s += p[sg * 64 + tid];  // conflict-free
        comb0[CH + tid] = s;
    } else if (tid < 2 * OUTF) {
        const float* p = (const float*)p4b;
        int o2 = tid - OUTF;
        float s = 0.0f;
#pragma unroll
        for (int sg = 0; sg < 16; ++sg) s += p[sg * 64 + o2];
        comb1[CH + o2] = s;
    }
    __syncthreads();

    // ---- update-KAN features: 256 threads build both rows' 1152 LDS rows ----
    {
        int rr = tid >> 7, c = tid & 127;
        const float* cb = rr ? comb1 : comb0;
        float* Fr = rr ? Fu1 : Fu0;
        float v = cb[c];
#pragma unroll
        for (int g = 0; g < 8; ++g) Fr[c * 9 + g] = 0.0f;
        Fr[c * 9 + 8] = silu(v);
        int d; float4 vv; spline4(v, d, vv);
#pragma unroll
        for (int k = 0; k < 4; ++k) {
            int m = d - 3 + k;
            if ((unsigned)m < 8u) Fr[c * 9 + m] = ((const float*)&vv)[k];
        }
    }
    __syncthreads();

    // ---- update matvec: each W2u float4 feeds both rows ----
    {
        const int o = tid & 63, w = tid >> 6;
        const float4* W = (const float4*)w2u;
        const float4* Fv0 = (const float4*)Fu0;
        const float4* Fv1 = (const float4*)Fu1;
        float a0 = 0.0f, a1 = 0.0f;
#pragma unroll 4
        for (int k4 = w * 72; k4 < w * 72 + 72; ++k4) {
            float4 f0 = Fv0[k4];
            float4 f1 = Fv1[k4];
            float4 wt = W[k4 * 64 + o];
            a0 += f0.x * wt.x + f0.y * wt.y + f0.z * wt.z + f0.w * wt.w;
            a1 += f1.x * wt.x + f1.y * wt.y + f1.z * wt.z + f1.w * wt.w;
        }
        p2a[w][o] = a0;
        p2b[w][o] = a1;
    }
    __syncthreads();
    if (tid < OUTF)
        out[(b * NB + i0) * OUTF + tid] =
            p2a[0][tid] + p2a[1][tid] + p2a[2][tid] + p2a[3][tid];
    else if (tid < 2 * OUTF) {
        int o2 = tid - OUTF;
        out[(b * NB + i1) * OUTF + o2] =
            p2b[0][o2] + p2b[1][o2] + p2b[2][o2] + p2b[3][o2];
    }
}

extern "C" void kernel_launch(void* const* d_in, const int* in_sizes, int n_in,
                              void* d_out, int out_size, void* d_ws, size_t ws_size,
                              hipStream_t stream) {
    const float* x     = (const float*)d_in[0];
    const int*   adj   = (const int*)d_in[1];
    const float* fwb   = (const float*)d_in[2];
    const float* fws   = (const float*)d_in[3];
    const float* fwsc  = (const float*)d_in[4];
    const float* mwb   = (const float*)d_in[5];
    const float* mws   = (const float*)d_in[6];
    const float* mwsc  = (const float*)d_in[7];
    const float* uwb   = (const float*)d_in[8];
    const float* uws   = (const float*)d_in[9];
    const float* uwsc  = (const float*)d_in[10];
    float* out = (float*)d_out;
    float* ws = (float*)d_ws;

    const int BN = in_sizes[0] / CH;   // 512

    const int prep_threads = KM4 * OUTF + KU4 * OUTF + CH * 16; // 28672
    prep_kernel<<<(prep_threads + 255) / 256, 256, 0, stream>>>(
        mwb, mws, mwsc, uwb, uws, uwsc, fws, fwsc, ws);
    msg_kernel<<<BN / 2, 256, 0, stream>>>(x, ws + WS_W2M, ws + WS_MSG);
    gat_kernel<<<BN / 2, 256, 0, stream>>>(x, adj, fwb, ws + WS_CPAD,
                                           ws + WS_W2U, ws + WS_MSG, out);
}